// Round 1
// baseline (715.491 us; speedup 1.0000x reference)
//
#include <hip/hip_runtime.h>

// RNN: B=512, T=1024, I=64, H=128, fp32 in/out.
// Round-4 theory: previous version was latency/sync-bound (~1207 cyc/step vs
// ~340 VALU-issue cyc/SIMD/step; VALUBusy 56%, HBM 1.6%, conflicts 0).
// Fix: 2 rows per block -> each wave carries two independent recurrences
// (guaranteed in-wave ILP across the barrier/LDS/tanh dependency stalls),
// one barrier per TWO row-steps, and the h-independent x-projection dots of
// step t+1 are software-pipelined into the barrier shadow of step t.
// Weights are shared across the two rows -> no extra weight VGPRs.
//  - 256 blocks x 256 thr: 1 block/CU, 4 waves; launch_bounds(256,2) caps
//    VGPR at 256 (no spill, ~150 expected) and permits 2-block co-residency.
// Precision unchanged: f16 weights/activations, fp32 accum via v_dot2.

#define Bsz 512
#define Tt  1024
#define Ii  64
#define Hh  128
constexpr int TC  = 32;          // timesteps per LDS chunk
constexpr int NT  = 256;         // threads per block (4 waves)
constexpr int RPB = 2;           // rows per block

typedef _Float16 half2v __attribute__((ext_vector_type(2)));
typedef _Float16 half4v __attribute__((ext_vector_type(4)));
typedef _Float16 half8v __attribute__((ext_vector_type(8)));

union h8u { half8v v; half2v h[4]; };   // subregister aliasing, no insts

__device__ __forceinline__ float dot2(half2v a, half2v b, float c) {
#if __has_builtin(__builtin_amdgcn_fdot2)
    return __builtin_amdgcn_fdot2(a, b, c, false);
#else
    return c + (float)a[0] * (float)b[0] + (float)a[1] * (float)b[1];
#endif
}

__device__ __forceinline__ float fast_tanh(float x) {
    float t = __builtin_amdgcn_exp2f(x * 2.8853900817779268f);
    return 1.0f - 2.0f * __builtin_amdgcn_rcpf(t + 1.0f);
}
__device__ __forceinline__ float fast_sigmoid(float z) {
    float t = __builtin_amdgcn_exp2f(-z * 1.4426950408889634f);
    return __builtin_amdgcn_rcpf(1.0f + t);
}
__device__ __forceinline__ half4v cvt4(float4 p) {
    half4v r; r[0] = (_Float16)p.x; r[1] = (_Float16)p.y;
    r[2] = (_Float16)p.z; r[3] = (_Float16)p.w; return r;
}

__global__ __launch_bounds__(NT, 2)   // 256-VGPR cap; 2 blocks/CU possible
void rnn_fused2(const float* __restrict__ x,
                const float* __restrict__ W_ih,
                const float* __restrict__ W_hh,
                const float* __restrict__ b_ih,
                const float* __restrict__ b_hh,
                const float* __restrict__ fc_w,
                const float* __restrict__ fc_b,
                float* __restrict__ out)
{
    __shared__ __align__(16) _Float16 xsh[2][RPB][TC * Ii];  // 16 KB
    __shared__ __align__(16) _Float16 hbuf[2][RPB][Hh];      // 1 KB
    __shared__ float wred[RPB][NT / 64];

    const int tid = threadIdx.x;
    const int kq  = tid & 3;           // K-quarter
    const int jg  = tid >> 2;          // 0..63 hidden-unit pair
    const int j0  = jg * 2, j1 = j0 + 1;
    const int rowA = blockIdx.x * RPB;
    const int rowB = rowA + 1;

    // ---- weights -> f16 registers (shared by both rows): 48 half2 ----
    half2v wih0[8], wih1[8];           // W_ih[j][kq*16 .. +16)
    {
        const float* g0 = W_ih + j0 * Ii + kq * 16;
        const float* g1 = W_ih + j1 * Ii + kq * 16;
        #pragma unroll
        for (int k = 0; k < 8; ++k) {
            wih0[k][0] = (_Float16)g0[2*k]; wih0[k][1] = (_Float16)g0[2*k+1];
            wih1[k][0] = (_Float16)g1[2*k]; wih1[k][1] = (_Float16)g1[2*k+1];
        }
    }
    half2v whh0[16], whh1[16];         // W_hh[j][kq*32 .. +32)
    {
        const float* g0 = W_hh + j0 * Hh + kq * 32;
        const float* g1 = W_hh + j1 * Hh + kq * 32;
        #pragma unroll
        for (int k = 0; k < 16; ++k) {
            whh0[k][0] = (_Float16)g0[2*k]; whh0[k][1] = (_Float16)g0[2*k+1];
            whh1[k][0] = (_Float16)g1[2*k]; whh1[k][1] = (_Float16)g1[2*k+1];
        }
    }
    const float bias0 = b_ih[j0] + b_hh[j0];
    const float bias1 = b_ih[j1] + b_hh[j1];
    const float fw0 = fc_w[j0], fw1 = fc_w[j1];

    if (tid < RPB * Hh / 2) ((half2v*)hbuf[0])[tid] = (half2v)0;   // h0 = 0, both rows

    // ---- x chunk prefetch: 2 float4/thread/row, stored as f16 ----
    const float4* xgA = (const float4*)(x + (size_t)rowA * Tt * Ii);
    const float4* xgB = (const float4*)(x + (size_t)rowB * Tt * Ii);
    float4 pA0 = xgA[tid], pA1 = xgA[tid + NT];
    float4 pB0 = xgB[tid], pB1 = xgB[tid + NT];

    float hA0 = 0.f, hA1 = 0.f, hB0 = 0.f, hB1 = 0.f;
    float fxA0, fxA1, fxA2, fxA3, fxB0, fxB1, fxB2, fxB3;  // pipelined x-dots

#define XDOT(TTv, CBv)                                                       \
    do {                                                                     \
        const half8v* xvA = (const half8v*)(xsh[CBv][0] + (TTv) * Ii) + kq*2;\
        const half8v* xvB = (const half8v*)(xsh[CBv][1] + (TTv) * Ii) + kq*2;\
        h8u xa0, xa1, xb0, xb1;                                              \
        xa0.v = xvA[0]; xa1.v = xvA[1];                                      \
        xb0.v = xvB[0]; xb1.v = xvB[1];                                      \
        fxA0 = 0.f; fxA1 = 0.f; fxA2 = 0.f; fxA3 = 0.f;                      \
        fxB0 = 0.f; fxB1 = 0.f; fxB2 = 0.f; fxB3 = 0.f;                      \
        _Pragma("unroll")                                                    \
        for (int k = 0; k < 4; ++k) {                                        \
            fxA0 = dot2(xa0.h[k], wih0[k],     fxA0);                        \
            fxA1 = dot2(xa1.h[k], wih0[k + 4], fxA1);                        \
            fxA2 = dot2(xa0.h[k], wih1[k],     fxA2);                        \
            fxA3 = dot2(xa1.h[k], wih1[k + 4], fxA3);                        \
            fxB0 = dot2(xb0.h[k], wih0[k],     fxB0);                        \
            fxB1 = dot2(xb1.h[k], wih0[k + 4], fxB1);                        \
            fxB2 = dot2(xb0.h[k], wih1[k],     fxB2);                        \
            fxB3 = dot2(xb1.h[k], wih1[k + 4], fxB3);                        \
        }                                                                    \
    } while (0)

    for (int t0 = 0; t0 < Tt; t0 += TC) {
        const int cb = (t0 / TC) & 1;
        ((half4v*)xsh[cb][0])[tid]      = cvt4(pA0);
        ((half4v*)xsh[cb][0])[tid + NT] = cvt4(pA1);
        ((half4v*)xsh[cb][1])[tid]      = cvt4(pB0);
        ((half4v*)xsh[cb][1])[tid + NT] = cvt4(pB1);
        if (t0 + TC < Tt) {
            const int base = (t0 + TC) * (Ii / 4);
            pA0 = xgA[base + tid]; pA1 = xgA[base + tid + NT];
            pB0 = xgB[base + tid]; pB1 = xgB[base + tid + NT];
        }
        __syncthreads();
        XDOT(0, cb);                     // x-part of first step of chunk

        #pragma unroll 2
        for (int tt = 0; tt < TC; ++tt) {
            const int hb = tt & 1;       // chunk len 32 is even -> starts at 0
            const half8v* hvA = (const half8v*)(hbuf[hb][0]) + kq * 4;
            const half8v* hvB = (const half8v*)(hbuf[hb][1]) + kq * 4;
            h8u ha0, ha1, ha2, ha3, hbq0, hbq1, hbq2, hbq3;
            ha0.v = hvA[0]; ha1.v = hvA[1]; ha2.v = hvA[2]; ha3.v = hvA[3];
            hbq0.v = hvB[0]; hbq1.v = hvB[1]; hbq2.v = hvB[2]; hbq3.v = hvB[3];

            float aA0 = fxA0, aA1 = fxA1, aA2 = 0.f, aA3 = 0.f;
            float cA0 = fxA2, cA1 = fxA3, cA2 = 0.f, cA3 = 0.f;
            float aB0 = fxB0, aB1 = fxB1, aB2 = 0.f, aB3 = 0.f;
            float cB0 = fxB2, cB1 = fxB3, cB2 = 0.f, cB3 = 0.f;
            #pragma unroll
            for (int k = 0; k < 4; ++k) {                 // 64 dot2: 16 indep chains
                aA0 = dot2(ha0.h[k], whh0[k],      aA0);
                aA1 = dot2(ha1.h[k], whh0[k + 4],  aA1);
                aA2 = dot2(ha2.h[k], whh0[k + 8],  aA2);
                aA3 = dot2(ha3.h[k], whh0[k + 12], aA3);
                cA0 = dot2(ha0.h[k], whh1[k],      cA0);
                cA1 = dot2(ha1.h[k], whh1[k + 4],  cA1);
                cA2 = dot2(ha2.h[k], whh1[k + 8],  cA2);
                cA3 = dot2(ha3.h[k], whh1[k + 12], cA3);
                aB0 = dot2(hbq0.h[k], whh0[k],      aB0);
                aB1 = dot2(hbq1.h[k], whh0[k + 4],  aB1);
                aB2 = dot2(hbq2.h[k], whh0[k + 8],  aB2);
                aB3 = dot2(hbq3.h[k], whh0[k + 12], aB3);
                cB0 = dot2(hbq0.h[k], whh1[k],      cB0);
                cB1 = dot2(hbq1.h[k], whh1[k + 4],  cB1);
                cB2 = dot2(hbq2.h[k], whh1[k + 8],  cB2);
                cB3 = dot2(hbq3.h[k], whh1[k + 12], cB3);
            }
            float ppA0 = (aA0 + aA1) + (aA2 + aA3);
            float ppA1 = (cA0 + cA1) + (cA2 + cA3);
            float ppB0 = (aB0 + aB1) + (aB2 + aB3);
            float ppB1 = (cB0 + cB1) + (cB2 + cB3);
            ppA0 += __shfl_xor(ppA0, 1, 64); ppA0 += __shfl_xor(ppA0, 2, 64);
            ppA1 += __shfl_xor(ppA1, 1, 64); ppA1 += __shfl_xor(ppA1, 2, 64);
            ppB0 += __shfl_xor(ppB0, 1, 64); ppB0 += __shfl_xor(ppB0, 2, 64);
            ppB1 += __shfl_xor(ppB1, 1, 64); ppB1 += __shfl_xor(ppB1, 2, 64);
            hA0 = fast_tanh(ppA0 + bias0);
            hA1 = fast_tanh(ppA1 + bias1);
            hB0 = fast_tanh(ppB0 + bias0);
            hB1 = fast_tanh(ppB1 + bias1);
            if (kq == 0) {
                half2v wA; wA[0] = (_Float16)hA0; wA[1] = (_Float16)hA1;
                half2v wB; wB[0] = (_Float16)hB0; wB[1] = (_Float16)hB1;
                ((half2v*)hbuf[hb ^ 1][0])[jg] = wA;
                ((half2v*)hbuf[hb ^ 1][1])[jg] = wB;
            }
            // pipelined x-dots for step tt+1 fill the barrier shadow
            if (tt != TC - 1) XDOT(tt + 1, cb);
            __syncthreads();
        }
    }

    // ---- epilogue: out[row] = sigmoid(fc_b + sum_j fc_w[j] * h[j]) ----
    float pA = (kq == 0) ? (fw0 * hA0 + fw1 * hA1) : 0.0f;
    float pB = (kq == 0) ? (fw0 * hB0 + fw1 * hB1) : 0.0f;
    #pragma unroll
    for (int off = 32; off > 0; off >>= 1) {
        pA += __shfl_down(pA, off, 64);
        pB += __shfl_down(pB, off, 64);
    }
    if ((tid & 63) == 0) { wred[0][tid >> 6] = pA; wred[1][tid >> 6] = pB; }
    __syncthreads();
    if (tid < RPB) {
        float z = fc_b[0];
        #pragma unroll
        for (int w = 0; w < NT / 64; ++w) z += wred[tid][w];
        out[rowA + tid] = fast_sigmoid(z);
    }
}

extern "C" void kernel_launch(void* const* d_in, const int* in_sizes, int n_in,
                              void* d_out, int out_size, void* d_ws, size_t ws_size,
                              hipStream_t stream) {
    const float* x    = (const float*)d_in[0];
    const float* W_ih = (const float*)d_in[1];
    const float* W_hh = (const float*)d_in[2];
    const float* b_ih = (const float*)d_in[3];
    const float* b_hh = (const float*)d_in[4];
    const float* fc_w = (const float*)d_in[5];
    const float* fc_b = (const float*)d_in[6];
    float* out = (float*)d_out;

    rnn_fused2<<<Bsz / RPB, NT, 0, stream>>>(x, W_ih, W_hh, b_ih, b_hh, fc_w, fc_b, out);
}